// Round 6
// baseline (298.426 us; speedup 1.0000x reference)
//
#include <hip/hip_runtime.h>
#include <math.h>

// Problem constants (B,S,D,H) = (4,2048,1024,16), HD=64
#define BATCH 4
#define SEQ   2048
#define DMODEL 1024
#define NHEAD 16
#define HDIM  64
#define MROWS (BATCH*SEQ)   // 8192

typedef unsigned short u16;
typedef unsigned int   u32;

using bf16x8 = __attribute__((ext_vector_type(8))) short;
using f32x4  = __attribute__((ext_vector_type(4))) float;
using f32x16 = __attribute__((ext_vector_type(16))) float;

__device__ __forceinline__ u16 f2bf(float f) {
    u32 u = __float_as_uint(f);
    u += 0x7fffu + ((u >> 16) & 1u);
    return (u16)(u >> 16);
}
__device__ __forceinline__ u32 pack2bf(float a, float b) {
    u32 ua = __float_as_uint(a); ua += 0x7fffu + ((ua >> 16) & 1u);
    u32 ub = __float_as_uint(b); ub += 0x7fffu + ((ub >> 16) & 1u);
    return (ua >> 16) | (ub & 0xffff0000u);
}

// async global->LDS, 16 B per lane; LDS dest = wave-uniform base + lane*16
#define GLOBAL_LOAD_LDS16(gp, lp)                                              \
    __builtin_amdgcn_global_load_lds(                                          \
        (const __attribute__((address_space(1))) void*)(gp),                   \
        (__attribute__((address_space(3))) void*)(lp), 16, 0, 0)

// ---------------------------------------------------------------------------
// Convert x (8.4M) + Wq/Wk/Wv/Wo (1M each) fp32 -> bf16 into contiguous dst.
// ---------------------------------------------------------------------------
__global__ __launch_bounds__(256) void convert_inputs(
    const float* __restrict__ x,  const float* __restrict__ wq,
    const float* __restrict__ wk, const float* __restrict__ wv,
    const float* __restrict__ wo, u16* __restrict__ dst)
{
    long long i4 = ((long long)blockIdx.x * 256 + threadIdx.x) * 4;
    const float* src; long long off;
    if (i4 < 8388608LL) { src = x; off = i4; }
    else {
        long long j = i4 - 8388608LL;
        int seg = (int)(j >> 20);
        off = j & 1048575LL;
        src = (seg == 0) ? wq : (seg == 1) ? wk : (seg == 2) ? wv : wo;
    }
    float4 v = *(const float4*)(src + off);
    u32 lo = (u32)f2bf(v.x) | ((u32)f2bf(v.y) << 16);
    u32 hi = (u32)f2bf(v.z) | ((u32)f2bf(v.w) << 16);
    *(uint2*)(dst + i4) = make_uint2(lo, hi);
}

// ---------------------------------------------------------------------------
// bf16 MFMA GEMM: C[M,N] = A[M,K] @ W[N,K]^T + bias.  128x128 tile, BK=32.
// Staging via global_load_lds (16B/lane). LDS rows = 32 shorts (64 B);
// XOR swizzle phys_chunk = logical ^ ((row>>1)&3) -> conflict-free b128 reads.
// XCD-aware block mapping (xcd = bx&7): each XCD keeps 2 MB of A L2-resident.
// QKV=1: seg 0/1/2 = Q/K/V; epilogue RoPE(+0.125*log2e) / RoPE / plain bf16.
//        NOTE: Q scale folds log2(e) so attention can use exp2 directly.
// QKV=0: fp32 output + bias (final projection).
// ---------------------------------------------------------------------------
template<int QKV>
__global__ __launch_bounds__(256) void gemm_mfma(
    const u16* __restrict__ A,
    const u16* __restrict__ Wq_, const u16* __restrict__ Wk_, const u16* __restrict__ Wv_,
    const float* __restrict__ bq_, const float* __restrict__ bk_, const float* __restrict__ bv_,
    u16* __restrict__ Cq_, u16* __restrict__ Ck_, u16* __restrict__ Cv_,
    float* __restrict__ Cf)
{
    __shared__ u16 As[128 * 32];
    __shared__ u16 Ws[128 * 32];

    const int t    = threadIdx.x;
    const int lane = t & 63;
    const int w    = t >> 6;
    const int quad = lane >> 4;
    const int l15  = lane & 15;

    const int bx  = blockIdx.x;
    const int xcd = bx & 7;
    const int i_  = bx >> 3;
    const int bml = i_ & 7;
    const int n_  = (QKV ? ((i_ >> 3) & 7) : (i_ >> 3));
    const int seg = (QKV ? (i_ >> 6) : 0);

    const u16*   W    = (seg == 0) ? Wq_ : (seg == 1) ? Wk_ : Wv_;
    const float* bias = (seg == 0) ? bq_ : (seg == 1) ? bk_ : bv_;
    u16*         Cb   = (seg == 0) ? Cq_ : (seg == 1) ? Ck_ : Cv_;

    const int bm   = (xcd * 8 + bml) * 128;
    const int bn   = n_ * 128;
    const int wrow = (w & 1) * 64;
    const int wcol = (w >> 1) * 64;

    const int srl = lane >> 2;
    const int sc  = (lane & 3) ^ ((lane >> 3) & 3);

    f32x4 acc[4][4] = {};

    for (int k0 = 0; k0 < DMODEL; k0 += 32) {
        __syncthreads();
        #pragma unroll
        for (int i = 0; i < 2; i++) {
            int row = 32 * w + 16 * i + srl;
            GLOBAL_LOAD_LDS16(A + (size_t)(bm + row) * DMODEL + k0 + sc * 8,
                              &As[(32 * w + 16 * i) * 32]);
            GLOBAL_LOAD_LDS16(W + (size_t)(bn + row) * DMODEL + k0 + sc * 8,
                              &Ws[(32 * w + 16 * i) * 32]);
        }
        __syncthreads();

        bf16x8 af[4], bfr[4];
        const int pc = quad ^ ((l15 >> 1) & 3);
        #pragma unroll
        for (int i = 0; i < 4; i++)
            af[i] = *(const bf16x8*)&As[(wrow + 16 * i + l15) * 32 + pc * 8];
        #pragma unroll
        for (int j = 0; j < 4; j++)
            bfr[j] = *(const bf16x8*)&Ws[(wcol + 16 * j + l15) * 32 + pc * 8];
        #pragma unroll
        for (int i = 0; i < 4; i++)
            #pragma unroll
            for (int j = 0; j < 4; j++)
                acc[i][j] = __builtin_amdgcn_mfma_f32_16x16x32_bf16(af[i], bfr[j], acc[i][j], 0, 0, 0);
    }

    // ---- epilogue
    float bv[4];
    #pragma unroll
    for (int j = 0; j < 4; j++) bv[j] = bias[bn + wcol + 16 * j + l15];

    if constexpr (QKV == 0) {
        #pragma unroll
        for (int i = 0; i < 4; i++)
            #pragma unroll
            for (int r = 0; r < 4; r++) {
                int mg = bm + wrow + 16 * i + quad * 4 + r;
                #pragma unroll
                for (int j = 0; j < 4; j++)
                    Cf[(size_t)mg * DMODEL + bn + wcol + 16 * j + l15] = acc[i][j][r] + bv[j];
            }
    } else {
        if (seg == 2) {
            #pragma unroll
            for (int i = 0; i < 4; i++)
                #pragma unroll
                for (int r = 0; r < 4; r++) {
                    int mg = bm + wrow + 16 * i + quad * 4 + r;
                    #pragma unroll
                    for (int j = 0; j < 4; j++)
                        Cb[(size_t)mg * DMODEL + bn + wcol + 16 * j + l15] = f2bf(acc[i][j][r] + bv[j]);
                }
        } else {
            // RoPE: wave's 64-col span = one head; pair (d, d+32) = j-tiles (j, j+2)
            // Q additionally scaled by 0.125*log2(e) so attention uses exp2.
            const float qscale = (seg == 0) ? 0.18033688011112042f : 1.0f;
            float inv[2];
            #pragma unroll
            for (int j = 0; j < 2; j++) {
                int d = 16 * j + l15;                              // 0..31
                inv[j] = exp2f(-(float)d * 0.4152410118609203f);   // 10000^(-d/32)
            }
            #pragma unroll
            for (int i = 0; i < 4; i++)
                #pragma unroll
                for (int r = 0; r < 4; r++) {
                    int mg = bm + wrow + 16 * i + quad * 4 + r;
                    int s  = mg & (SEQ - 1);
                    #pragma unroll
                    for (int j = 0; j < 2; j++) {
                        float f = (float)s * inv[j];
                        float sn, cs;
                        __sincosf(f, &sn, &cs);
                        float a1 = acc[i][j][r]     + bv[j];
                        float a2 = acc[i][j + 2][r] + bv[j + 2];
                        float o1 = (a1 * cs - a2 * sn) * qscale;
                        float o2 = (a2 * cs + a1 * sn) * qscale;
                        Cb[(size_t)mg * DMODEL + bn + wcol + 16 * j       + l15] = f2bf(o1);
                        Cb[(size_t)mg * DMODEL + bn + wcol + 16 * (j + 2) + l15] = f2bf(o2);
                    }
                }
        }
    }
}

// ---------------------------------------------------------------------------
// MFMA flash attention v3: 32x32x16 MFMA, 64 q-rows/block, 2 waves (128 thr),
// max-free softmax with exp2 (log2e folded into Q at GEMM epilogue).
// LDS: QPs (Q tile, reused as P after fragment hoist) + Ks + Vt = 24.25 KB
// -> 6 blocks/CU.  Grid 2048 (heavy q-tiles first).
// All LDS tiles: 64-short rows (128 B), swizzle phys_chunk = logical ^ (row&7).
// ---------------------------------------------------------------------------
__global__ __launch_bounds__(128) void attn_mfma(
    const u16* __restrict__ Q, const u16* __restrict__ K,
    const u16* __restrict__ V, u16* __restrict__ O)
{
    __shared__ u16 QPs[64 * 64];   // Q tile, then P tile (wave-private rows)
    __shared__ u16 Ks[64 * 64];
    __shared__ u16 Vt[64 * 64];
    __shared__ float lS[64];

    const int t    = threadIdx.x;
    const int lane = t & 63;
    const int w    = t >> 6;            // 0/1: wave owns q rows [32w, 32w+32)
    const int l31  = lane & 31;
    const int hl   = lane >> 5;         // 0/1
    const int bid  = blockIdx.x;
    const int bh   = bid & 63;
    const int qt   = 31 - (bid >> 6);   // heavy q-tiles first
    const int h    = bh & (NHEAD - 1);
    const int b    = bh >> 4;
    const int q0   = qt * 64;

    const size_t gbase = ((size_t)b * SEQ) * DMODEL + h * HDIM;

    // ---- stage Q tile (64 rows) via global_load_lds, swizzled (key = row&7)
    {
        int rl = lane >> 3, cp = lane & 7;
        int c  = cp ^ rl;               // logical chunk
        #pragma unroll
        for (int i = 0; i < 4; i++) {
            int row = 32 * w + 8 * i + rl;
            GLOBAL_LOAD_LDS16(Q + gbase + (size_t)(q0 + row) * DMODEL + c * 8,
                              &QPs[(32 * w + 8 * i) * 64]);
        }
    }
    __syncthreads();

    // ---- hoist Q B-fragments (loop-invariant): B[k][n=q], k = 8hl+16s+j
    const int qrow = 32 * w + l31;      // local q row
    const int qg   = q0 + qrow;         // global q row
    bf16x8 qf[4];
    #pragma unroll
    for (int s = 0; s < 4; s++) {
        int c = (hl + 2 * s) ^ (qrow & 7);
        qf[s] = *(const bf16x8*)&QPs[qrow * 64 + c * 8];
    }

    float lsum = 0.0f;
    f32x16 oacc[2] = {};

    for (int kt = 0; kt <= qt; kt++) {
        const int k0 = kt * 64;
        __syncthreads();   // prior readers of Ks/Vt/QPs done; hoist done (iter 0)

        // ---- stage K (64 rows) via global_load_lds, swizzled
        {
            int rl = lane >> 3, cp = lane & 7;
            int c  = cp ^ rl;
            #pragma unroll
            for (int i = 0; i < 4; i++) {
                int row = 32 * w + 8 * i + rl;
                GLOBAL_LOAD_LDS16(K + gbase + (size_t)(k0 + row) * DMODEL + c * 8,
                                  &Ks[(32 * w + 8 * i) * 64]);
            }
        }
        // ---- stage V transposed: Vt[d][j] = V[k0+j][d], pair-packed, swizzled.
        //      thread: rows 2u,2u+1 (u=t>>2), d-chunks v and v+4 (v=t&3)
        //      -> 64-B contiguous runs per 4 lanes (good L2 cacheline use)
        {
            int u = t >> 2, v = t & 3;
            int j0 = 2 * u;
            #pragma unroll
            for (int half = 0; half < 2; half++) {
                int ch = v + 4 * half;           // d-chunk (8 u16)
                int d0 = ch * 8;
                uint4 va = *(const uint4*)(V + gbase + (size_t)(k0 + j0)     * DMODEL + d0);
                uint4 vb = *(const uint4*)(V + gbase + (size_t)(k0 + j0 + 1) * DMODEL + d0);
                const u16* pa = (const u16*)&va;
                const u16* pb = (const u16*)&vb;
                int pos = u & 3, kch = u >> 2;   // jd = u -> chunk u>>2, pos u&3
                #pragma unroll
                for (int e = 0; e < 8; e++) {
                    int row  = d0 + e;
                    int pcch = kch ^ (row & 7);
                    *(u32*)&Vt[row * 64 + pcch * 8 + pos * 2] = (u32)pa[e] | ((u32)pb[e] << 16);
                }
            }
        }
        __syncthreads();

        const bool diagt = (kt == qt);
        #pragma unroll
        for (int krh = 0; krh < 2; krh++) {
            if (diagt && krh > w) {
                // fully masked quadrant: P = 0
                #pragma unroll
                for (int g = 0; g < 4; g++)
                    #pragma unroll
                    for (int pp = 0; pp < 2; pp++) {
                        int jd  = 16 * krh + 4 * g + 2 * hl + pp;
                        int pcc = (jd >> 2) ^ (qrow & 7);
                        *(u32*)&QPs[qrow * 64 + pcc * 8 + (jd & 3) * 2] = 0u;
                    }
                continue;
            }
            // ---- S^T quadrant: D[m=kr][n=q]
            f32x16 s = {};
            #pragma unroll
            for (int stp = 0; stp < 4; stp++) {
                int row = 32 * krh + l31;
                int c   = (hl + 2 * stp) ^ (row & 7);
                bf16x8 ka = *(const bf16x8*)&Ks[row * 64 + c * 8];
                s = __builtin_amdgcn_mfma_f32_32x32x16_bf16(ka, qf[stp], s, 0, 0, 0);
            }
            // causal mask on diagonal-crossing tiles
            if (diagt && krh == w) {
                #pragma unroll
                for (int r = 0; r < 16; r++) {
                    int krg = k0 + 32 * krh + (r & 3) + 8 * (r >> 2) + 4 * hl;
                    if (krg > qg) s[r] = -1e30f;
                }
            }
            // ---- exp2 (max-free; log2e pre-folded), accumulate l, pack P
            float pv[16];
            #pragma unroll
            for (int r = 0; r < 16; r++) { pv[r] = exp2f(s[r]); lsum += pv[r]; }
            #pragma unroll
            for (int g = 0; g < 4; g++)
                #pragma unroll
                for (int pp = 0; pp < 2; pp++) {
                    int jd  = 16 * krh + 4 * g + 2 * hl + pp;
                    int pcc = (jd >> 2) ^ (qrow & 7);
                    *(u32*)&QPs[qrow * 64 + pcc * 8 + (jd & 3) * 2] =
                        pack2bf(pv[4 * g + 2 * pp], pv[4 * g + 2 * pp + 1]);
                }
        }

        // ---- O += P @ V   (A = P rows q [wave-private], B = Vt rows d)
        #pragma unroll
        for (int stp = 0; stp < 4; stp++) {
            int c = (hl + 2 * stp) ^ (qrow & 7);
            bf16x8 pf = *(const bf16x8*)&QPs[qrow * 64 + c * 8];
            #pragma unroll
            for (int dh = 0; dh < 2; dh++) {
                int vr = 32 * dh + l31;
                bf16x8 vf = *(const bf16x8*)&Vt[vr * 64 + ((hl + 2 * stp) ^ (vr & 7)) * 8];
                oacc[dh] = __builtin_amdgcn_mfma_f32_32x32x16_bf16(pf, vf, oacc[dh], 0, 0, 0);
            }
        }
    }

    // ---- finalize l (cross-half reduce, through LDS to reindex q)
    lsum += __shfl_xor(lsum, 32, 64);
    if (hl == 0) lS[32 * w + l31] = lsum;
    __syncthreads();

    // ---- writeout: O / l   (C layout: col=l31=d-local, row=(r&3)+8*(r>>2)+4hl)
    #pragma unroll
    for (int g = 0; g < 4; g++) {
        f32x4 lv = *(const f32x4*)&lS[32 * w + 8 * g + 4 * hl];
        #pragma unroll
        for (int rr = 0; rr < 4; rr++) {
            int qgw = q0 + 32 * w + rr + 8 * g + 4 * hl;
            float inv = 1.0f / lv[rr];
            #pragma unroll
            for (int dh = 0; dh < 2; dh++) {
                float o = oacc[dh][4 * g + rr] * inv;
                O[gbase + (size_t)qgw * DMODEL + 32 * dh + l31] = f2bf(o);
            }
        }
    }
}

// ---------------------------------------------------------------------------
extern "C" void kernel_launch(void* const* d_in, const int* in_sizes, int n_in,
                              void* d_out, int out_size, void* d_ws, size_t ws_size,
                              hipStream_t stream)
{
    const float* x  = (const float*)d_in[0];
    const float* Wq = (const float*)d_in[1];
    const float* bq = (const float*)d_in[2];
    const float* Wk = (const float*)d_in[3];
    const float* bk = (const float*)d_in[4];
    const float* Wv = (const float*)d_in[5];
    const float* bv = (const float*)d_in[6];
    const float* Wo = (const float*)d_in[7];
    const float* bo = (const float*)d_in[8];

    u16* wsp = (u16*)d_ws;
    u16* xb  = wsp;                    // 8388608
    u16* Wqb = wsp + 8388608;          // 1048576 each
    u16* Wkb = Wqb + 1048576;
    u16* Wvb = Wkb + 1048576;
    u16* Wob = Wvb + 1048576;
    u16* Qb  = Wob + 1048576;          // 8388608 each
    u16* Kb  = Qb + 8388608;
    u16* Vb  = Kb + 8388608;
    u16* Ab  = Vb + 8388608;

    convert_inputs<<<12288, 256, 0, stream>>>(x, Wq, Wk, Wv, Wo, xb);

    gemm_mfma<1><<<1536, 256, 0, stream>>>(xb, Wqb, Wkb, Wvb, bq, bk, bv,
                                           Qb, Kb, Vb, nullptr);

    attn_mfma<<<2048, 128, 0, stream>>>(Qb, Kb, Vb, Ab);

    gemm_mfma<0><<<512, 256, 0, stream>>>(Ab, Wob, nullptr, nullptr, bo, nullptr, nullptr,
                                          nullptr, nullptr, nullptr, (float*)d_out);
}